// Round 1
// baseline (1524.987 us; speedup 1.0000x reference)
//
#include <hip/hip_runtime.h>

// Problem constants (fixed by the reference).
#define NSRC  16384
#define NDST  8192
#define NN    50
#define DF    64
#define KSEL  10
#define PITCH 51   // 50 + 1: odd word stride -> conflict-free LDS column access

__global__ void zero_deg_kernel(int* __restrict__ deg) {
    int i = blockIdx.x * blockDim.x + threadIdx.x;
    if (i < NSRC) deg[i] = 0;
}

__global__ void count_kernel(const int* __restrict__ nbr, int* __restrict__ deg) {
    int i = blockIdx.x * blockDim.x + threadIdx.x;
    if (i < NDST * NN) atomicAdd(&deg[nbr[i]], 1);
}

__global__ void norm_kernel(const int* __restrict__ deg, float* __restrict__ norm) {
    int i = blockIdx.x * blockDim.x + threadIdx.x;
    if (i < NSRC) {
        float d = fmaxf((float)deg[i], 1.0f);
        norm[i] = 1.0f / sqrtf(d);
    }
}

// One block per dst. Stage the 50x50 sims tile in LDS, run the greedy
// max-coverage selection, then write the normalized feature sum.
__global__ __launch_bounds__(256) void main_kernel(
    const float* __restrict__ h_src,
    const float* __restrict__ sims_table,
    const int*   __restrict__ nbr,
    const float* __restrict__ norm,
    float*       __restrict__ out)
{
    __shared__ float s[NN * PITCH];   // 10.2 KB
    __shared__ float cache[NN];
    __shared__ float gains[NN];
    __shared__ int   nidx[NN];
    __shared__ int   sels[KSEL];

    const int b = blockIdx.x;
    const int t = threadIdx.x;

    if (t < NN) {
        nidx[t]  = nbr[b * NN + t];
        cache[t] = 0.0f;
    }
    __syncthreads();

    // Gather 2500 random elements of sims_table into LDS.
    for (int e = t; e < NN * NN; e += 256) {
        int i = e / NN;
        int j = e - i * NN;
        s[i * PITCH + j] = sims_table[(size_t)nidx[i] * NSRC + (size_t)nidx[j]];
    }
    __syncthreads();

    // Greedy selection: K rounds of (gain per candidate, argmax, cache update).
    for (int k = 0; k < KSEL; ++k) {
        if (t < NN) {
            const float* row = &s[t * PITCH];
            // Bit-exact emulation of numpy pairwise_sum for n=50:
            // r[u] accumulates j = u, 8+u, ..., 40+u; combine pairwise; tail 48,49.
            float r[8];
            #pragma unroll
            for (int u = 0; u < 8; ++u) {
                float c = cache[u];
                r[u] = fmaxf(row[u], c) - c;
            }
            #pragma unroll
            for (int j0 = 8; j0 < 48; j0 += 8) {
                #pragma unroll
                for (int u = 0; u < 8; ++u) {
                    float c = cache[j0 + u];
                    r[u] += fmaxf(row[j0 + u], c) - c;
                }
            }
            float res = ((r[0] + r[1]) + (r[2] + r[3])) + ((r[4] + r[5]) + (r[6] + r[7]));
            float c48 = cache[48]; res += fmaxf(row[48], c48) - c48;
            float c49 = cache[49]; res += fmaxf(row[49], c49) - c49;
            gains[t] = res;
        }
        __syncthreads();
        if (t == 0) {
            // First-max wins (strict >) == jnp/np.argmax tie semantics.
            float best = gains[0]; int bi = 0;
            for (int i = 1; i < NN; ++i) {
                float g = gains[i];
                if (g > best) { best = g; bi = i; }
            }
            sels[k] = bi;
        }
        __syncthreads();
        int sel = sels[k];
        if (t < NN) cache[t] = fmaxf(cache[t], s[sel * PITCH + t]);
        __syncthreads();
    }

    // Output: sum the 10 selected (normalized) feature rows, scale by 50^-0.5.
    if (t < DF) {
        float acc = 0.0f;
        #pragma unroll
        for (int k = 0; k < KSEL; ++k) {
            int sidx = nidx[sels[k]];
            acc += h_src[(size_t)sidx * DF + t] * norm[sidx];
        }
        out[(size_t)b * DF + t] = acc * 0.14142135623730950488f;
    }
}

extern "C" void kernel_launch(void* const* d_in, const int* in_sizes, int n_in,
                              void* d_out, int out_size, void* d_ws, size_t ws_size,
                              hipStream_t stream) {
    const float* h_src = (const float*)d_in[0];
    const float* sims  = (const float*)d_in[1];
    const int*   nbr   = (const int*)d_in[2];
    float* out = (float*)d_out;

    int*   deg  = (int*)d_ws;
    float* norm = (float*)((char*)d_ws + (size_t)NSRC * sizeof(int));

    zero_deg_kernel<<<(NSRC + 255) / 256, 256, 0, stream>>>(deg);
    count_kernel<<<(NDST * NN + 255) / 256, 256, 0, stream>>>(nbr, deg);
    norm_kernel<<<(NSRC + 255) / 256, 256, 0, stream>>>(deg, norm);
    main_kernel<<<NDST, 256, 0, stream>>>(h_src, sims, nbr, norm, out);
}

// Round 2
// 1520.689 us; speedup vs baseline: 1.0028x; 1.0028x over previous
//
#include <hip/hip_runtime.h>

// Problem constants (fixed by the reference).
#define NSRC  16384
#define NDST  8192
#define NN    50
#define DF    64
#define KSEL  10
#define PITCH 51   // 50 + 1: odd word stride -> conflict-free LDS column access

__global__ void zero_deg_kernel(int* __restrict__ deg) {
    int i = blockIdx.x * blockDim.x + threadIdx.x;
    if (i < NSRC) deg[i] = 0;
}

__global__ void count_kernel(const int* __restrict__ nbr, int* __restrict__ deg) {
    int i = blockIdx.x * blockDim.x + threadIdx.x;
    if (i < NDST * NN) atomicAdd(&deg[nbr[i]], 1);
}

__global__ void norm_kernel(const int* __restrict__ deg, float* __restrict__ norm) {
    int i = blockIdx.x * blockDim.x + threadIdx.x;
    if (i < NSRC) {
        float d = fmaxf((float)deg[i], 1.0f);
        norm[i] = 1.0f / sqrtf(d);
    }
}

// One block per dst. 256 threads gather the 50x50 sims tile into LDS; then
// wave 0 alone runs the greedy selection entirely in registers + read-only
// LDS (no barriers, shuffle-based argmax), then writes the output row.
__global__ __launch_bounds__(256) void main_kernel(
    const float* __restrict__ h_src,
    const float* __restrict__ sims_table,
    const int*   __restrict__ nbr,
    const float* __restrict__ norm,
    float*       __restrict__ out)
{
    __shared__ float s[NN * PITCH];   // 10.2 KB, read-only after gather barrier
    __shared__ int   nidx[NN];

    const int b = blockIdx.x;
    const int t = threadIdx.x;

    if (t < NN) nidx[t] = nbr[b * NN + t];
    __syncthreads();

    // Gather 2500 random elements of sims_table into LDS.
    // 10 independent loads per thread (threads 196..255 do 9).
    #pragma unroll
    for (int u = 0; u < 10; ++u) {
        int e = t + u * 256;
        if (e < NN * NN) {
            int i = e / NN;
            int j = e - i * NN;
            s[i * PITCH + j] = sims_table[(size_t)nidx[i] * NSRC + (size_t)nidx[j]];
        }
    }
    __syncthreads();

    if (t >= 64) return;   // waves 1..3 done; wave 0 finishes alone

    // Greedy selection, wave-synchronous: lane t owns cache[t] in a register.
    float cache_r = 0.0f;
    int   sels_r[KSEL];

    const float* row = &s[t * PITCH];   // only dereferenced when t < NN

    #pragma unroll
    for (int k = 0; k < KSEL; ++k) {
        float g;
        if (t < NN) {
            // Bit-exact emulation of numpy pairwise_sum for n=50:
            // r[u] accumulates j = u, 8+u, ..., 40+u; combine pairwise; tail 48,49.
            float r[8];
            #pragma unroll
            for (int u = 0; u < 8; ++u) {
                float c = __shfl(cache_r, u);
                r[u] = fmaxf(row[u], c) - c;
            }
            #pragma unroll
            for (int j0 = 8; j0 < 48; j0 += 8) {
                #pragma unroll
                for (int u = 0; u < 8; ++u) {
                    float c = __shfl(cache_r, j0 + u);
                    r[u] += fmaxf(row[j0 + u], c) - c;
                }
            }
            float res = ((r[0] + r[1]) + (r[2] + r[3])) + ((r[4] + r[5]) + (r[6] + r[7]));
            float c48 = __shfl(cache_r, 48); res += fmaxf(row[48], c48) - c48;
            float c49 = __shfl(cache_r, 49); res += fmaxf(row[49], c49) - c49;
            g = res;
        } else {
            g = -1.0f;    // real gains are >= 0; dummies never win
        }

        // Wave argmax with first-index-wins tiebreak (== np.argmax).
        int idx = t;
        #pragma unroll
        for (int off = 32; off >= 1; off >>= 1) {
            float og = __shfl_xor(g, off);
            int   oi = __shfl_xor(idx, off);
            if (og > g || (og == g && oi < idx)) { g = og; idx = oi; }
        }
        sels_r[k] = idx;

        if (t < NN) cache_r = fmaxf(cache_r, s[idx * PITCH + t]);
    }

    // Output: sum the 10 selected (normalized) feature rows, scale by 50^-0.5.
    float acc = 0.0f;
    #pragma unroll
    for (int k = 0; k < KSEL; ++k) {
        int sidx = nidx[sels_r[k]];
        acc += h_src[(size_t)sidx * DF + t] * norm[sidx];
    }
    out[(size_t)b * DF + t] = acc * 0.14142135623730950488f;
}

extern "C" void kernel_launch(void* const* d_in, const int* in_sizes, int n_in,
                              void* d_out, int out_size, void* d_ws, size_t ws_size,
                              hipStream_t stream) {
    const float* h_src = (const float*)d_in[0];
    const float* sims  = (const float*)d_in[1];
    const int*   nbr   = (const int*)d_in[2];
    float* out = (float*)d_out;

    int*   deg  = (int*)d_ws;
    float* norm = (float*)((char*)d_ws + (size_t)NSRC * sizeof(int));

    zero_deg_kernel<<<(NSRC + 255) / 256, 256, 0, stream>>>(deg);
    count_kernel<<<(NDST * NN + 255) / 256, 256, 0, stream>>>(nbr, deg);
    norm_kernel<<<(NSRC + 255) / 256, 256, 0, stream>>>(deg, norm);
    main_kernel<<<NDST, 256, 0, stream>>>(h_src, sims, nbr, norm, out);
}